// Round 9
// baseline (349.008 us; speedup 1.0000x reference)
//
#include <hip/hip_runtime.h>
#include <hip/hip_bf16.h>

#define NN 2048
#define BB 8
#define TROW 128928   // sum_{d=1..64} (2047-d)

// ---------------- k_left: R[b][i][k] = dot(x[b,i,:], wl[k,:]), k=(c*3+dh) in [0,15) ----------
// grid 512 = 8 b x 64 rowgroups(32 rows); block 256 = 4 waves; wave handles 8 rows (120 acc).
// Key: 15 wl loads per segment amortized over 8 rows (960 cy FMA per 23 loads) -> wave covers
// its own L2/HBM latency. Epilogue folds 64->16 lanes via shfl; LDS 32.6 KB.
// Side jobs: blocks 0..127 fill WF (transposed wr); block 0 zeroes psum.
__global__ __launch_bounds__(256) void k_left(const float* __restrict__ x,
                                              const float* __restrict__ wl,
                                              const float* __restrict__ wr,
                                              float* __restrict__ R,
                                              float* __restrict__ WF,
                                              float* __restrict__ psum) {
    if (blockIdx.x == 0 && threadIdx.x < 64) psum[threadIdx.x] = 0.f;
    if (blockIdx.x < 128) {
        int idx = blockIdx.x * 256 + threadIdx.x;  // 32768 = 2048*16
        int h = idx >> 4, k = idx & 15;
        float v = 0.f;
        if (k < 15) {
            int c = k / 3, dw = k - c * 3;
            v = wr[c * (NN * 3) + h * 3 + dw];
        }
        WF[idx] = v;
    }
    __shared__ float red[4][120 * 17];
    int b = blockIdx.x >> 6;
    int rg = blockIdx.x & 63;
    int wv = threadIdx.x >> 6, lane = threadIdx.x & 63;
    int r0 = rg * 32 + wv * 8;
    const float* xp = x + ((size_t)(b * NN + r0)) * NN;

    float acc[8][15];
#pragma unroll
    for (int r = 0; r < 8; r++)
#pragma unroll
        for (int k = 0; k < 15; k++) acc[r][k] = 0.f;

    for (int seg = 0; seg < 8; seg++) {
        int j0 = seg * 256 + lane * 4;
        float4 xv[8];
#pragma unroll
        for (int r = 0; r < 8; r++) xv[r] = *(const float4*)(xp + (size_t)r * NN + j0);
#pragma unroll
        for (int k = 0; k < 15; k++) {
            float4 w4 = *(const float4*)(wl + (size_t)k * NN + j0);
#pragma unroll
            for (int r = 0; r < 8; r++) {
                acc[r][k] = fmaf(xv[r].x, w4.x, acc[r][k]);
                acc[r][k] = fmaf(xv[r].y, w4.y, acc[r][k]);
                acc[r][k] = fmaf(xv[r].z, w4.z, acc[r][k]);
                acc[r][k] = fmaf(xv[r].w, w4.w, acc[r][k]);
            }
        }
    }
    // fold 64 lanes -> 16, then small-LDS reduce
#pragma unroll
    for (int r = 0; r < 8; r++)
#pragma unroll
        for (int k = 0; k < 15; k++) {
            float v = acc[r][k];
            v += __shfl_down(v, 32);
            v += __shfl_down(v, 16);
            if (lane < 16) red[wv][(r * 15 + k) * 17 + lane] = v;
        }
    __syncthreads();
#pragma unroll
    for (int base = 0; base < 120; base += 64) {
        int idx = base + lane;
        if (idx < 120) {
            const float* rp = &red[wv][idx * 17];
            float s = 0.f;
#pragma unroll
            for (int j = 0; j < 16; j++) s += rp[j];
            int r = idx / 15, k = idx - r * 15;
            R[(size_t)(b * NN + r0 + r) * 16 + k] = s;
        }
    }
}

// ---------------- k_right: CSp[rc][b][k][j] = sum_{h in rc chunk} x[b,h,j]*WF[h][k] ----------
// grid 256 = 8 b x 2 jc(1024 cols) x 16 rc(128 rows); block 512 = 8 waves.
// Wave owns 128 cols (lane*2 within), iterates ALL 128 rows -> complete partial, no LDS.
// Weights via block-uniform loads from WF (s_load path). 30 acc/thread, 8 loads in flight.
__global__ __launch_bounds__(512) void k_right(const float* __restrict__ x,
                                               const float* __restrict__ WF,
                                               float* __restrict__ CSp) {
    int b = blockIdx.x >> 5;
    int rem = blockIdx.x & 31;
    int jc = rem >> 4, rc = rem & 15;
    int r0 = rc * 128;
    int w = threadIdx.x >> 6, lane = threadIdx.x & 63;
    int c0 = jc * 1024 + w * 128 + lane * 2;
    const float* xp = x + ((size_t)b * NN + r0) * NN + c0;

    float acc[15][2];
#pragma unroll
    for (int k = 0; k < 15; k++) { acc[k][0] = 0.f; acc[k][1] = 0.f; }

    for (int rb = 0; rb < 16; rb++) {
        float2 xv[8];
#pragma unroll
        for (int q = 0; q < 8; q++)
            xv[q] = *(const float2*)(xp + (size_t)(rb * 8 + q) * NN);
#pragma unroll
        for (int q = 0; q < 8; q++) {
            const float* wrow = WF + (size_t)(r0 + rb * 8 + q) * 16;  // block-uniform -> SGPR
#pragma unroll
            for (int k = 0; k < 15; k++) {
                float wk = wrow[k];
                acc[k][0] = fmaf(xv[q].x, wk, acc[k][0]);
                acc[k][1] = fmaf(xv[q].y, wk, acc[k][1]);
            }
        }
    }
    float* outp = CSp + ((size_t)(rc * BB + b) * 16) * NN + c0;
#pragma unroll
    for (int k = 0; k < 15; k++) {
        float2 v; v.x = acc[k][0]; v.y = acc[k][1];
        *(float2*)(outp + (size_t)k * NN) = v;
    }
}

// ---------------- k_csum: CS[b][k][j] = sum_{rc<16} CSp[rc][b][k][j] -------------------------
// grid 256 x block 256; thread handles one float4 (65536 total).
__global__ __launch_bounds__(256) void k_csum(const float* __restrict__ CSp,
                                              float* __restrict__ CS) {
    int vid = blockIdx.x * 256 + threadIdx.x;  // float4 index in [0, 65536)
    const float4* src = (const float4*)CSp;
    float4 s = src[vid];
#pragma unroll
    for (int rc = 1; rc < 16; rc++) {
        float4 v = src[vid + rc * 65536];
        s.x += v.x; s.y += v.y; s.z += v.z; s.w += v.w;
    }
    ((float4*)CS)[vid] = s;
}

// ---------------- k_chainC: combine(R,CS)+bias -> 6 conv layers -> sigmoid head --------------
// grid 128 = 8 b x 16 chunks(128 cols); halo 6 each side -> ext 140 positions.
__global__ __launch_bounds__(256) void k_chainC(const float* __restrict__ R,
                                                const float* __restrict__ CS,
                                                const float* __restrict__ bl,
                                                const float* __restrict__ br,
                                                const float* __restrict__ wA, const float* __restrict__ bA,
                                                const float* __restrict__ wB, const float* __restrict__ bB,
                                                const float* __restrict__ wT, const float* __restrict__ bT,
                                                const float* __restrict__ wm, const float* __restrict__ bm,
                                                float* __restrict__ LEFT, float* __restrict__ RIGHT) {
    __shared__ float buf0[10][144], buf1[10][144];
    __shared__ float W[3][10][10][3];
    __shared__ float Bs[3][10];
    __shared__ float Wm[2][10], Bm[2];
    int b = blockIdx.x >> 4;
    int c0 = (blockIdx.x & 15) << 7;
    int tid = threadIdx.x;

    for (int idx = tid; idx < 900; idx += 256) {
        int set = idx / 300, rem = idx - set * 300;
        int o = rem / 30, rem2 = rem - o * 30, c = rem2 / 3, kk = rem2 - c * 3;
        float u;
        if (set == 0) u = wA[o * 30 + c * 3 + kk];
        else if (set == 1) u = wB[o * 30 + c * 3 + kk];
        else u = wT[c * 30 + o * 3 + (2 - kk)];   // wTc[o,c,k] = wT[c,o,2-k]
        W[set][o][c][kk] = u;
    }
    if (tid < 30) {
        float v = (tid < 10) ? bA[tid] : (tid < 20) ? bB[tid - 10] : bT[tid - 20];
        Bs[tid / 10][tid % 10] = v;
    }
    if (tid < 20) Wm[tid / 10][tid % 10] = wm[tid];
    if (tid < 2) Bm[tid] = bm[tid];

    // fused combine: build the 10x140 input window directly from R / CS
    for (int idx = tid; idx < 1400; idx += 256) {
        int ch = idx / 140, p = idx - ch * 140;
        int g = c0 - 6 + p;
        float v = 0.f;
        if (g >= 0 && g < NN) {
            if (ch < 5) {
                v = bl[ch];
#pragma unroll
                for (int dh = 0; dh < 3; dh++) {
                    int r = g + dh - 1;
                    if (r >= 0 && r < NN) v += R[(size_t)(b * NN + r) * 16 + ch * 3 + dh];
                }
            } else {
                int c = ch - 5;
                v = br[c];
#pragma unroll
                for (int dw = 0; dw < 3; dw++) {
                    int j = g + dw - 1;
                    if (j >= 0 && j < NN)
                        v += CS[((size_t)b * 16 + c * 3 + dw) * NN + j];
                }
            }
        }
        buf0[ch][p] = v;
    }
    __syncthreads();

    float(*in)[144] = buf0;
    float(*out)[144] = buf1;
    for (int layer = 0; layer < 6; layer++) {
        int set = (layer == 0) ? 0 : (layer < 3 ? 1 : 2);
        int lo = layer + 1;  // valid p range [lo, 140-lo)
        for (int idx = tid; idx < 1400; idx += 256) {
            int o = idx / 140, p = idx - o * 140;
            if (p >= lo && p < 140 - lo) {
                float s = Bs[set][o];
#pragma unroll
                for (int c = 0; c < 10; c++) {
                    const float* ip = &in[c][p];
                    s = fmaf(ip[-1], W[set][o][c][0], s);
                    s = fmaf(ip[0], W[set][o][c][1], s);
                    s = fmaf(ip[1], W[set][o][c][2], s);
                }
                s = s > 0.f ? s : 0.f;
                int g = c0 - 6 + p;
                if (g < 0 || g >= NN) s = 0.f;  // reproduce zero padding at global edges
                out[o][p] = s;
            }
        }
        __syncthreads();
        float(*tmp)[144] = in; in = out; out = tmp;
    }
    // 1x1 conv to 2ch + sigmoid; write the 128 owned cols
    {
        int idx = tid;  // 256 = 2 ch x 128 cols
        int o = idx >> 7, pp = idx & 127;
        int p = 6 + pp;
        float s = Bm[o];
#pragma unroll
        for (int c = 0; c < 10; c++) s = fmaf(in[c][p], Wm[o][c], s);
        float sig = 1.f / (1.f + __expf(-s));
        (o ? RIGHT : LEFT)[b * NN + c0 + pp] = sig;
    }
}

// ---------------- k_diagmass: stage exp(diag) tile, compute p, write P + psum atomics --------
// grid 256 = 8 b x 32 i-tiles(64); block 256 = 4 waves; wave wv handles dm1 = wv*16..wv*16+15.
__global__ __launch_bounds__(256) void k_diagmass(const float* __restrict__ x,
                                                  const float* __restrict__ LEFT,
                                                  const float* __restrict__ RIGHT,
                                                  float* __restrict__ P,
                                                  float* __restrict__ psum) {
    __shared__ float T[65][65];   // T[r][dm1] = exp(x[b, i0+r, i0+r+dm1+1]), +1 halo row
    __shared__ float psl[64];
    int b = blockIdx.x >> 5;
    int i0 = (blockIdx.x & 31) << 6;
    int tid = threadIdx.x;

    // stage: 65 rows x 64 diag offsets, coalesced along the row
    for (int idx = tid; idx < 65 * 64; idx += 256) {
        int r = idx >> 6, dm1 = idx & 63;
        int row = i0 + r;
        int col = row + dm1 + 1;
        float v = 0.f;
        if (row < NN && col < NN) v = __expf(x[((size_t)b * NN + row) * NN + col]);
        T[r][dm1] = v;
    }
    __syncthreads();

    int wv = tid >> 6, lane = tid & 63;
    int i = i0 + lane;
    const float* lf = LEFT + b * NN;
    const float* rt = RIGHT + b * NN;
#pragma unroll
    for (int s = 0; s < 16; s++) {
        int dm1 = wv * 16 + s;
        int d = dm1 + 1;
        int L = (NN - 1) - d;
        float p = 0.f;
        if (i < L) {
            float mi = T[lane + 1][dm1] * rt[i + 1] + T[lane][dm1] * lf[d + i];
            float mo = rt[i] + lf[d + 1 + i];
            p = __logf(mi / mo);
            P[((size_t)dm1 * BB + b) * NN + i] = p;
        }
        float s64 = p;
        for (int off = 32; off; off >>= 1) s64 += __shfl_down(s64, off);
        if (lane == 0) psl[dm1] = s64;
    }
    __syncthreads();
    if (tid < 64) atomicAdd(&psum[tid], psl[tid]);
}

// ---------------- k_out: out = P - psum[d]/(8L), f32 ------------------------------------------
__global__ __launch_bounds__(1024) void k_out(const float* __restrict__ P,
                                              const float* __restrict__ psum,
                                              float* __restrict__ outp) {
    int dm1 = blockIdx.x >> 2, q = blockIdx.x & 3;
    int d = dm1 + 1;
    int L = (NN - 1) - d;
    int tid = threadIdx.x;
    int b2 = tid >> 9, ii = tid & 511;
    int i = q * 512 + ii;
    if (i >= L) return;
    float mean = psum[dm1] / (float)(8 * L);
    size_t off0 = (size_t)dm1 * (NN - 1) - (size_t)dm1 * (dm1 + 1) / 2;
#pragma unroll
    for (int bs = 0; bs < 4; bs++) {
        int b = b2 + bs * 2;
        outp[(size_t)b * TROW + off0 + i] = P[((size_t)dm1 * BB + b) * NN + i] - mean;
    }
}

extern "C" void kernel_launch(void* const* d_in, const int* in_sizes, int n_in,
                              void* d_out, int out_size, void* d_ws, size_t ws_size,
                              hipStream_t stream) {
    const float* x = (const float*)d_in[0];
    const float* wl = (const float*)d_in[1];
    const float* bl = (const float*)d_in[2];
    const float* wr = (const float*)d_in[3];
    const float* br = (const float*)d_in[4];
    const float* wA = (const float*)d_in[5];
    const float* bA = (const float*)d_in[6];
    const float* wB = (const float*)d_in[7];
    const float* bB = (const float*)d_in[8];
    const float* wT = (const float*)d_in[9];
    const float* bT = (const float*)d_in[10];
    const float* wm = (const float*)d_in[11];
    const float* bm = (const float*)d_in[12];

    float* ws = (float*)d_ws;
    float* R    = ws;              // 8*2048*16        = 262144 f
    float* CSp  = ws + 262144;     // 16*8*16*2048     = 4194304 f
    float* WF   = ws + 4456448;    // 2048*16          = 32768 f
    float* CS   = ws + 4489216;    // 8*16*2048        = 262144 f
    float* LEFT = ws + 4751360;    // 8*2048           = 16384 f
    float* RIGHT= ws + 4767744;    // 8*2048           = 16384 f
    float* P    = ws + 4784128;    // 64*8*2048        = 1048576 f
    float* psum = ws + 5832704;    // 64 f

    k_left<<<512, 256, 0, stream>>>(x, wl, wr, R, WF, psum);
    k_right<<<256, 512, 0, stream>>>(x, WF, CSp);
    k_csum<<<256, 256, 0, stream>>>(CSp, CS);
    k_chainC<<<128, 256, 0, stream>>>(R, CS, bl, br, wA, bA, wB, bB, wT, bT, wm, bm, LEFT, RIGHT);
    k_diagmass<<<256, 256, 0, stream>>>(x, LEFT, RIGHT, P, psum);
    k_out<<<256, 1024, 0, stream>>>(P, psum, (float*)d_out);
}

// Round 10
// 305.879 us; speedup vs baseline: 1.1410x; 1.1410x over previous
//
#include <hip/hip_runtime.h>
#include <hip/hip_bf16.h>

#define NN 2048
#define BB 8
#define TROW 128928   // sum_{d=1..64} (2047-d)

typedef __attribute__((ext_vector_type(8))) short bf16x8;
typedef __attribute__((ext_vector_type(4))) float f32x4;

__device__ __forceinline__ short f2bf(float f) {
    unsigned u = __float_as_uint(f);
    unsigned r = (u + 0x7FFFu + ((u >> 16) & 1u)) >> 16;   // RNE
    return (short)r;
}

// ---------------- k_leftm: R partials via MFMA. C = X(16384x2048) . wl^T(2048x15) -------------
// grid 1024 = 8 b x 32 rowgroups(64) x 4 K-splits(512); block 256 = 4 waves; wave = 16 rows.
// A-frag: lane(q=lane>>4,m=lane&15) holds x[r0+m][k0+q*8+j], j=0..7 (2 float4 -> bf16x8).
// B-frag: same pattern from wl row n=lane&15 (row 15 clamped to 14; D col 15 unused).
// D: col=lane&15(=ch), row=q*4+reg. Side jobs: blocks 0..127 fill WF; block 0 zeroes psum.
__global__ __launch_bounds__(256) void k_leftm(const float* __restrict__ x,
                                               const float* __restrict__ wl,
                                               const float* __restrict__ wr,
                                               float* __restrict__ Rp,
                                               float* __restrict__ WF,
                                               float* __restrict__ psum) {
    if (blockIdx.x == 0 && threadIdx.x < 64) psum[threadIdx.x] = 0.f;
    if (blockIdx.x < 128) {
        int idx = blockIdx.x * 256 + threadIdx.x;  // 32768 = 2048*16
        int h = idx >> 4, k = idx & 15;
        float v = 0.f;
        if (k < 15) {
            int c = k / 3, dw = k - c * 3;
            v = wr[c * (NN * 3) + h * 3 + dw];
        }
        WF[idx] = v;
    }
    int b = blockIdx.x >> 7;
    int sub = blockIdx.x & 127;
    int rg = sub >> 2, ks = sub & 3;
    int wv = threadIdx.x >> 6, lane = threadIdx.x & 63;
    int q = lane >> 4, m = lane & 15;
    int r0 = rg * 64 + wv * 16;
    int nrow = (m == 15) ? 14 : m;
    int k0 = ks * 512 + q * 8;

    const float* ap = x + ((size_t)(b * NN + r0 + m)) * NN + k0;
    const float* bp = wl + (size_t)nrow * NN + k0;

    f32x4 acc = {0.f, 0.f, 0.f, 0.f};
#pragma unroll 4
    for (int it = 0; it < 16; it++) {
        const float* a0 = ap + it * 32;
        const float* b0 = bp + it * 32;
        float4 av0 = *(const float4*)(a0);
        float4 av1 = *(const float4*)(a0 + 4);
        float4 bv0 = *(const float4*)(b0);
        float4 bv1 = *(const float4*)(b0 + 4);
        bf16x8 af, bf;
        af[0] = f2bf(av0.x); af[1] = f2bf(av0.y); af[2] = f2bf(av0.z); af[3] = f2bf(av0.w);
        af[4] = f2bf(av1.x); af[5] = f2bf(av1.y); af[6] = f2bf(av1.z); af[7] = f2bf(av1.w);
        bf[0] = f2bf(bv0.x); bf[1] = f2bf(bv0.y); bf[2] = f2bf(bv0.z); bf[3] = f2bf(bv0.w);
        bf[4] = f2bf(bv1.x); bf[5] = f2bf(bv1.y); bf[6] = f2bf(bv1.z); bf[7] = f2bf(bv1.w);
        acc = __builtin_amdgcn_mfma_f32_16x16x32_bf16(af, bf, acc, 0, 0, 0);
    }
    // D: row = q*4+reg (within 16-row tile), col = m
    float* rp = Rp + (size_t)ks * 262144 + ((size_t)b * NN + r0) * 16;
#pragma unroll
    for (int reg = 0; reg < 4; reg++)
        rp[(q * 4 + reg) * 16 + m] = acc[reg];
}

// ---------------- k_right: CSp[rc][b][k][j] = sum_{h in rc chunk} x[b,h,j]*WF[h][k] ----------
// grid 256 = 8 b x 2 jc(1024 cols) x 16 rc(128 rows); block 512 = 8 waves.
__global__ __launch_bounds__(512) void k_right(const float* __restrict__ x,
                                               const float* __restrict__ WF,
                                               float* __restrict__ CSp) {
    int b = blockIdx.x >> 5;
    int rem = blockIdx.x & 31;
    int jc = rem >> 4, rc = rem & 15;
    int r0 = rc * 128;
    int w = threadIdx.x >> 6, lane = threadIdx.x & 63;
    int c0 = jc * 1024 + w * 128 + lane * 2;
    const float* xp = x + ((size_t)b * NN + r0) * NN + c0;

    float acc[15][2];
#pragma unroll
    for (int k = 0; k < 15; k++) { acc[k][0] = 0.f; acc[k][1] = 0.f; }

    for (int rb = 0; rb < 16; rb++) {
        float2 xv[8];
#pragma unroll
        for (int q = 0; q < 8; q++)
            xv[q] = *(const float2*)(xp + (size_t)(rb * 8 + q) * NN);
#pragma unroll
        for (int q = 0; q < 8; q++) {
            const float* wrow = WF + (size_t)(r0 + rb * 8 + q) * 16;  // block-uniform -> SGPR
#pragma unroll
            for (int k = 0; k < 15; k++) {
                float wk = wrow[k];
                acc[k][0] = fmaf(xv[q].x, wk, acc[k][0]);
                acc[k][1] = fmaf(xv[q].y, wk, acc[k][1]);
            }
        }
    }
    float* outp = CSp + ((size_t)(rc * BB + b) * 16) * NN + c0;
#pragma unroll
    for (int k = 0; k < 15; k++) {
        float2 v; v.x = acc[k][0]; v.y = acc[k][1];
        *(float2*)(outp + (size_t)k * NN) = v;
    }
}

// ---------------- k_csum: CS = sum_rc CSp (blocks 0..255); R = sum_ks Rp (blocks 256..511) ---
__global__ __launch_bounds__(256) void k_csum(const float* __restrict__ CSp,
                                              float* __restrict__ CS,
                                              const float* __restrict__ Rp,
                                              float* __restrict__ R) {
    int blk = blockIdx.x;
    if (blk < 256) {
        int vid = blk * 256 + threadIdx.x;  // float4 index in [0, 65536)
        const float4* src = (const float4*)CSp;
        float4 s = src[vid];
#pragma unroll
        for (int rc = 1; rc < 16; rc++) {
            float4 v = src[vid + rc * 65536];
            s.x += v.x; s.y += v.y; s.z += v.z; s.w += v.w;
        }
        ((float4*)CS)[vid] = s;
    } else {
        int vid = (blk - 256) * 256 + threadIdx.x;  // float4 index in [0, 65536)
        const float4* src = (const float4*)Rp;
        float4 s = src[vid];
#pragma unroll
        for (int ks = 1; ks < 4; ks++) {
            float4 v = src[vid + ks * 65536];
            s.x += v.x; s.y += v.y; s.z += v.z; s.w += v.w;
        }
        ((float4*)R)[vid] = s;
    }
}

// ---------------- k_chainC: combine(R,CS)+bias -> 6 conv layers -> sigmoid head --------------
// grid 128 = 8 b x 16 chunks(128 cols); halo 6 each side -> ext 140 positions.
__global__ __launch_bounds__(256) void k_chainC(const float* __restrict__ R,
                                                const float* __restrict__ CS,
                                                const float* __restrict__ bl,
                                                const float* __restrict__ br,
                                                const float* __restrict__ wA, const float* __restrict__ bA,
                                                const float* __restrict__ wB, const float* __restrict__ bB,
                                                const float* __restrict__ wT, const float* __restrict__ bT,
                                                const float* __restrict__ wm, const float* __restrict__ bm,
                                                float* __restrict__ LEFT, float* __restrict__ RIGHT) {
    __shared__ float buf0[10][144], buf1[10][144];
    __shared__ float W[3][10][10][3];
    __shared__ float Bs[3][10];
    __shared__ float Wm[2][10], Bm[2];
    int b = blockIdx.x >> 4;
    int c0 = (blockIdx.x & 15) << 7;
    int tid = threadIdx.x;

    for (int idx = tid; idx < 900; idx += 256) {
        int set = idx / 300, rem = idx - set * 300;
        int o = rem / 30, rem2 = rem - o * 30, c = rem2 / 3, kk = rem2 - c * 3;
        float u;
        if (set == 0) u = wA[o * 30 + c * 3 + kk];
        else if (set == 1) u = wB[o * 30 + c * 3 + kk];
        else u = wT[c * 30 + o * 3 + (2 - kk)];   // wTc[o,c,k] = wT[c,o,2-k]
        W[set][o][c][kk] = u;
    }
    if (tid < 30) {
        float v = (tid < 10) ? bA[tid] : (tid < 20) ? bB[tid - 10] : bT[tid - 20];
        Bs[tid / 10][tid % 10] = v;
    }
    if (tid < 20) Wm[tid / 10][tid % 10] = wm[tid];
    if (tid < 2) Bm[tid] = bm[tid];

    // fused combine: build the 10x140 input window directly from R / CS
    for (int idx = tid; idx < 1400; idx += 256) {
        int ch = idx / 140, p = idx - ch * 140;
        int g = c0 - 6 + p;
        float v = 0.f;
        if (g >= 0 && g < NN) {
            if (ch < 5) {
                v = bl[ch];
#pragma unroll
                for (int dh = 0; dh < 3; dh++) {
                    int r = g + dh - 1;
                    if (r >= 0 && r < NN) v += R[(size_t)(b * NN + r) * 16 + ch * 3 + dh];
                }
            } else {
                int c = ch - 5;
                v = br[c];
#pragma unroll
                for (int dw = 0; dw < 3; dw++) {
                    int j = g + dw - 1;
                    if (j >= 0 && j < NN)
                        v += CS[((size_t)b * 16 + c * 3 + dw) * NN + j];
                }
            }
        }
        buf0[ch][p] = v;
    }
    __syncthreads();

    float(*in)[144] = buf0;
    float(*out)[144] = buf1;
    for (int layer = 0; layer < 6; layer++) {
        int set = (layer == 0) ? 0 : (layer < 3 ? 1 : 2);
        int lo = layer + 1;  // valid p range [lo, 140-lo)
        for (int idx = tid; idx < 1400; idx += 256) {
            int o = idx / 140, p = idx - o * 140;
            if (p >= lo && p < 140 - lo) {
                float s = Bs[set][o];
#pragma unroll
                for (int c = 0; c < 10; c++) {
                    const float* ip = &in[c][p];
                    s = fmaf(ip[-1], W[set][o][c][0], s);
                    s = fmaf(ip[0], W[set][o][c][1], s);
                    s = fmaf(ip[1], W[set][o][c][2], s);
                }
                s = s > 0.f ? s : 0.f;
                int g = c0 - 6 + p;
                if (g < 0 || g >= NN) s = 0.f;  // reproduce zero padding at global edges
                out[o][p] = s;
            }
        }
        __syncthreads();
        float(*tmp)[144] = in; in = out; out = tmp;
    }
    // 1x1 conv to 2ch + sigmoid; write the 128 owned cols
    {
        int idx = tid;  // 256 = 2 ch x 128 cols
        int o = idx >> 7, pp = idx & 127;
        int p = 6 + pp;
        float s = Bm[o];
#pragma unroll
        for (int c = 0; c < 10; c++) s = fmaf(in[c][p], Wm[o][c], s);
        float sig = 1.f / (1.f + __expf(-s));
        (o ? RIGHT : LEFT)[b * NN + c0 + pp] = sig;
    }
}

// ---------------- k_diagmass: stage exp(diag) tile, compute p, write P + psum atomics --------
// grid 256 = 8 b x 32 i-tiles(64); block 256 = 4 waves; wave wv handles dm1 = wv*16..wv*16+15.
__global__ __launch_bounds__(256) void k_diagmass(const float* __restrict__ x,
                                                  const float* __restrict__ LEFT,
                                                  const float* __restrict__ RIGHT,
                                                  float* __restrict__ P,
                                                  float* __restrict__ psum) {
    __shared__ float T[65][65];   // T[r][dm1] = exp(x[b, i0+r, i0+r+dm1+1]), +1 halo row
    __shared__ float psl[64];
    int b = blockIdx.x >> 5;
    int i0 = (blockIdx.x & 31) << 6;
    int tid = threadIdx.x;

    // stage: 65 rows x 64 diag offsets, coalesced along the row
    for (int idx = tid; idx < 65 * 64; idx += 256) {
        int r = idx >> 6, dm1 = idx & 63;
        int row = i0 + r;
        int col = row + dm1 + 1;
        float v = 0.f;
        if (row < NN && col < NN) v = __expf(x[((size_t)b * NN + row) * NN + col]);
        T[r][dm1] = v;
    }
    __syncthreads();

    int wv = tid >> 6, lane = tid & 63;
    int i = i0 + lane;
    const float* lf = LEFT + b * NN;
    const float* rt = RIGHT + b * NN;
#pragma unroll
    for (int s = 0; s < 16; s++) {
        int dm1 = wv * 16 + s;
        int d = dm1 + 1;
        int L = (NN - 1) - d;
        float p = 0.f;
        if (i < L) {
            float mi = T[lane + 1][dm1] * rt[i + 1] + T[lane][dm1] * lf[d + i];
            float mo = rt[i] + lf[d + 1 + i];
            p = __logf(mi / mo);
            P[((size_t)dm1 * BB + b) * NN + i] = p;
        }
        float s64 = p;
        for (int off = 32; off; off >>= 1) s64 += __shfl_down(s64, off);
        if (lane == 0) psl[dm1] = s64;
    }
    __syncthreads();
    if (tid < 64) atomicAdd(&psum[tid], psl[tid]);
}

// ---------------- k_out: out = P - psum[d]/(8L), f32 ------------------------------------------
__global__ __launch_bounds__(1024) void k_out(const float* __restrict__ P,
                                              const float* __restrict__ psum,
                                              float* __restrict__ outp) {
    int dm1 = blockIdx.x >> 2, q = blockIdx.x & 3;
    int d = dm1 + 1;
    int L = (NN - 1) - d;
    int tid = threadIdx.x;
    int b2 = tid >> 9, ii = tid & 511;
    int i = q * 512 + ii;
    if (i >= L) return;
    float mean = psum[dm1] / (float)(8 * L);
    size_t off0 = (size_t)dm1 * (NN - 1) - (size_t)dm1 * (dm1 + 1) / 2;
#pragma unroll
    for (int bs = 0; bs < 4; bs++) {
        int b = b2 + bs * 2;
        outp[(size_t)b * TROW + off0 + i] = P[((size_t)dm1 * BB + b) * NN + i] - mean;
    }
}

extern "C" void kernel_launch(void* const* d_in, const int* in_sizes, int n_in,
                              void* d_out, int out_size, void* d_ws, size_t ws_size,
                              hipStream_t stream) {
    const float* x = (const float*)d_in[0];
    const float* wl = (const float*)d_in[1];
    const float* bl = (const float*)d_in[2];
    const float* wr = (const float*)d_in[3];
    const float* br = (const float*)d_in[4];
    const float* wA = (const float*)d_in[5];
    const float* bA = (const float*)d_in[6];
    const float* wB = (const float*)d_in[7];
    const float* bB = (const float*)d_in[8];
    const float* wT = (const float*)d_in[9];
    const float* bT = (const float*)d_in[10];
    const float* wm = (const float*)d_in[11];
    const float* bm = (const float*)d_in[12];

    float* ws = (float*)d_ws;
    float* R    = ws;              // 8*2048*16        = 262144 f
    float* Rp   = ws + 262144;     // 4*8*2048*16      = 1048576 f
    float* CSp  = ws + 1310720;    // 16*8*16*2048     = 4194304 f
    float* WF   = ws + 5505024;    // 2048*16          = 32768 f
    float* CS   = ws + 5537792;    // 8*16*2048        = 262144 f
    float* LEFT = ws + 5799936;    // 8*2048           = 16384 f
    float* RIGHT= ws + 5816320;    // 8*2048           = 16384 f
    float* P    = ws + 5832704;    // 64*8*2048        = 1048576 f
    float* psum = ws + 6881280;    // 64 f

    k_leftm<<<1024, 256, 0, stream>>>(x, wl, wr, Rp, WF, psum);
    k_right<<<256, 512, 0, stream>>>(x, WF, CSp);
    k_csum<<<512, 256, 0, stream>>>(CSp, CS, Rp, R);
    k_chainC<<<128, 256, 0, stream>>>(R, CS, bl, br, wA, bA, wB, bB, wT, bT, wm, bm, LEFT, RIGHT);
    k_diagmass<<<256, 256, 0, stream>>>(x, LEFT, RIGHT, P, psum);
    k_out<<<256, 1024, 0, stream>>>(P, psum, (float*)d_out);
}

// Round 11
// 296.019 us; speedup vs baseline: 1.1790x; 1.0333x over previous
//
#include <hip/hip_runtime.h>
#include <hip/hip_bf16.h>

#define NN 2048
#define BB 8
#define TROW 128928   // sum_{d=1..64} (2047-d)

typedef __attribute__((ext_vector_type(8))) short bf16x8;
typedef __attribute__((ext_vector_type(4))) float f32x4;

__device__ __forceinline__ short f2bf(float f) {
    unsigned u = __float_as_uint(f);
    unsigned r = (u + 0x7FFFu + ((u >> 16) & 1u)) >> 16;   // RNE
    return (short)r;
}

// ---------------- k_stage1: fused left(MFMA) + right(column-sums) ----------------------------
// blocks 0..1023: Rp partials via MFMA. C = X(16384x2048) . wl^T(2048x15).
//   grid-part 1024 = 8 b x 32 rowgroups(64) x 4 K-splits(512); wave = 16 rows.
//   A-frag: lane(q,m) holds x[r0+m][k0+q*8+j]; B-frag from wl row m (15 clamped); D col=m,row=q*4+reg.
// blocks 1024..1279: CSp[rc][b][k][j] partial column sums; thread owns 4 cols, 128 rows;
//   weights read directly from wr via block-uniform scalar loads (s_load, L2-hot).
// block 0 zeroes psum[64] + counter.
__global__ __launch_bounds__(256) void k_stage1(const float* __restrict__ x,
                                                const float* __restrict__ wl,
                                                const float* __restrict__ wr,
                                                float* __restrict__ Rp,
                                                float* __restrict__ CSp,
                                                float* __restrict__ psum,
                                                int* __restrict__ counter) {
    int blk = blockIdx.x;
    int tid = threadIdx.x;
    if (blk == 0 && tid < 65) {
        if (tid < 64) psum[tid] = 0.f;
        else *counter = 0;
    }
    if (blk < 1024) {
        // ---- MFMA row-dot path ----
        int b = blk >> 7;
        int sub = blk & 127;
        int rg = sub >> 2, ks = sub & 3;
        int wv = tid >> 6, lane = tid & 63;
        int q = lane >> 4, m = lane & 15;
        int r0 = rg * 64 + wv * 16;
        int nrow = (m == 15) ? 14 : m;
        int k0 = ks * 512 + q * 8;

        const float* ap = x + ((size_t)(b * NN + r0 + m)) * NN + k0;
        const float* bp = wl + (size_t)nrow * NN + k0;

        f32x4 acc = {0.f, 0.f, 0.f, 0.f};
#pragma unroll 4
        for (int it = 0; it < 16; it++) {
            const float* a0 = ap + it * 32;
            const float* b0 = bp + it * 32;
            float4 av0 = *(const float4*)(a0);
            float4 av1 = *(const float4*)(a0 + 4);
            float4 bv0 = *(const float4*)(b0);
            float4 bv1 = *(const float4*)(b0 + 4);
            bf16x8 af, bf;
            af[0] = f2bf(av0.x); af[1] = f2bf(av0.y); af[2] = f2bf(av0.z); af[3] = f2bf(av0.w);
            af[4] = f2bf(av1.x); af[5] = f2bf(av1.y); af[6] = f2bf(av1.z); af[7] = f2bf(av1.w);
            bf[0] = f2bf(bv0.x); bf[1] = f2bf(bv0.y); bf[2] = f2bf(bv0.z); bf[3] = f2bf(bv0.w);
            bf[4] = f2bf(bv1.x); bf[5] = f2bf(bv1.y); bf[6] = f2bf(bv1.z); bf[7] = f2bf(bv1.w);
            acc = __builtin_amdgcn_mfma_f32_16x16x32_bf16(af, bf, acc, 0, 0, 0);
        }
        float* rp = Rp + (size_t)ks * 262144 + ((size_t)b * NN + r0) * 16;
#pragma unroll
        for (int reg = 0; reg < 4; reg++)
            rp[(q * 4 + reg) * 16 + m] = acc[reg];
    } else {
        // ---- column-sum path ----
        int blk2 = blk - 1024;
        int b = blk2 >> 5;
        int rem = blk2 & 31;
        int jc = rem >> 4, rc = rem & 15;
        int r0 = rc * 128;
        int c0 = jc * 1024 + tid * 4;
        const float* xp = x + ((size_t)b * NN + r0) * NN + c0;

        float acc[15][4];
#pragma unroll
        for (int k = 0; k < 15; k++)
#pragma unroll
            for (int e = 0; e < 4; e++) acc[k][e] = 0.f;

        for (int rb = 0; rb < 16; rb++) {
            float4 xv[8];
#pragma unroll
            for (int q = 0; q < 8; q++)
                xv[q] = *(const float4*)(xp + (size_t)(rb * 8 + q) * NN);
#pragma unroll
            for (int q = 0; q < 8; q++) {
                int h = r0 + rb * 8 + q;
#pragma unroll
                for (int k = 0; k < 15; k++) {
                    int c = k / 3, dw = k - c * 3;
                    float wk = wr[c * (NN * 3) + h * 3 + dw];  // block-uniform -> s_load
                    acc[k][0] = fmaf(xv[q].x, wk, acc[k][0]);
                    acc[k][1] = fmaf(xv[q].y, wk, acc[k][1]);
                    acc[k][2] = fmaf(xv[q].z, wk, acc[k][2]);
                    acc[k][3] = fmaf(xv[q].w, wk, acc[k][3]);
                }
            }
        }
        float* outp = CSp + ((size_t)(rc * BB + b) * 16) * NN + c0;
#pragma unroll
        for (int k = 0; k < 15; k++) {
            float4 v; v.x = acc[k][0]; v.y = acc[k][1]; v.z = acc[k][2]; v.w = acc[k][3];
            *(float4*)(outp + (size_t)k * NN) = v;
        }
    }
}

// ---------------- k_csum: CS = sum_rc CSp (blocks 0..255); R = sum_ks Rp (blocks 256..511) ---
__global__ __launch_bounds__(256) void k_csum(const float* __restrict__ CSp,
                                              float* __restrict__ CS,
                                              const float* __restrict__ Rp,
                                              float* __restrict__ R) {
    int blk = blockIdx.x;
    if (blk < 256) {
        int vid = blk * 256 + threadIdx.x;  // float4 index in [0, 65536)
        const float4* src = (const float4*)CSp;
        float4 s = src[vid];
#pragma unroll
        for (int rc = 1; rc < 16; rc++) {
            float4 v = src[vid + rc * 65536];
            s.x += v.x; s.y += v.y; s.z += v.z; s.w += v.w;
        }
        ((float4*)CS)[vid] = s;
    } else {
        int vid = (blk - 256) * 256 + threadIdx.x;  // float4 index in [0, 65536)
        const float4* src = (const float4*)Rp;
        float4 s = src[vid];
#pragma unroll
        for (int ks = 1; ks < 4; ks++) {
            float4 v = src[vid + ks * 65536];
            s.x += v.x; s.y += v.y; s.z += v.z; s.w += v.w;
        }
        ((float4*)R)[vid] = s;
    }
}

// ---------------- k_chainC: combine(R,CS)+bias -> 6 conv layers -> sigmoid head --------------
// grid 128 = 8 b x 16 chunks(128 cols); halo 6 each side -> ext 140 positions.
__global__ __launch_bounds__(256) void k_chainC(const float* __restrict__ R,
                                                const float* __restrict__ CS,
                                                const float* __restrict__ bl,
                                                const float* __restrict__ br,
                                                const float* __restrict__ wA, const float* __restrict__ bA,
                                                const float* __restrict__ wB, const float* __restrict__ bB,
                                                const float* __restrict__ wT, const float* __restrict__ bT,
                                                const float* __restrict__ wm, const float* __restrict__ bm,
                                                float* __restrict__ LEFT, float* __restrict__ RIGHT) {
    __shared__ float buf0[10][144], buf1[10][144];
    __shared__ float W[3][10][10][3];
    __shared__ float Bs[3][10];
    __shared__ float Wm[2][10], Bm[2];
    int b = blockIdx.x >> 4;
    int c0 = (blockIdx.x & 15) << 7;
    int tid = threadIdx.x;

    for (int idx = tid; idx < 900; idx += 256) {
        int set = idx / 300, rem = idx - set * 300;
        int o = rem / 30, rem2 = rem - o * 30, c = rem2 / 3, kk = rem2 - c * 3;
        float u;
        if (set == 0) u = wA[o * 30 + c * 3 + kk];
        else if (set == 1) u = wB[o * 30 + c * 3 + kk];
        else u = wT[c * 30 + o * 3 + (2 - kk)];   // wTc[o,c,k] = wT[c,o,2-k]
        W[set][o][c][kk] = u;
    }
    if (tid < 30) {
        float v = (tid < 10) ? bA[tid] : (tid < 20) ? bB[tid - 10] : bT[tid - 20];
        Bs[tid / 10][tid % 10] = v;
    }
    if (tid < 20) Wm[tid / 10][tid % 10] = wm[tid];
    if (tid < 2) Bm[tid] = bm[tid];

    // fused combine: build the 10x140 input window directly from R / CS
    for (int idx = tid; idx < 1400; idx += 256) {
        int ch = idx / 140, p = idx - ch * 140;
        int g = c0 - 6 + p;
        float v = 0.f;
        if (g >= 0 && g < NN) {
            if (ch < 5) {
                v = bl[ch];
#pragma unroll
                for (int dh = 0; dh < 3; dh++) {
                    int r = g + dh - 1;
                    if (r >= 0 && r < NN) v += R[(size_t)(b * NN + r) * 16 + ch * 3 + dh];
                }
            } else {
                int c = ch - 5;
                v = br[c];
#pragma unroll
                for (int dw = 0; dw < 3; dw++) {
                    int j = g + dw - 1;
                    if (j >= 0 && j < NN)
                        v += CS[((size_t)b * 16 + c * 3 + dw) * NN + j];
                }
            }
        }
        buf0[ch][p] = v;
    }
    __syncthreads();

    float(*in)[144] = buf0;
    float(*out)[144] = buf1;
    for (int layer = 0; layer < 6; layer++) {
        int set = (layer == 0) ? 0 : (layer < 3 ? 1 : 2);
        int lo = layer + 1;  // valid p range [lo, 140-lo)
        for (int idx = tid; idx < 1400; idx += 256) {
            int o = idx / 140, p = idx - o * 140;
            if (p >= lo && p < 140 - lo) {
                float s = Bs[set][o];
#pragma unroll
                for (int c = 0; c < 10; c++) {
                    const float* ip = &in[c][p];
                    s = fmaf(ip[-1], W[set][o][c][0], s);
                    s = fmaf(ip[0], W[set][o][c][1], s);
                    s = fmaf(ip[1], W[set][o][c][2], s);
                }
                s = s > 0.f ? s : 0.f;
                int g = c0 - 6 + p;
                if (g < 0 || g >= NN) s = 0.f;  // reproduce zero padding at global edges
                out[o][p] = s;
            }
        }
        __syncthreads();
        float(*tmp)[144] = in; in = out; out = tmp;
    }
    // 1x1 conv to 2ch + sigmoid; write the 128 owned cols
    {
        int idx = tid;  // 256 = 2 ch x 128 cols
        int o = idx >> 7, pp = idx & 127;
        int p = 6 + pp;
        float s = Bm[o];
#pragma unroll
        for (int c = 0; c < 10; c++) s = fmaf(in[c][p], Wm[o][c], s);
        float sig = 1.f / (1.f + __expf(-s));
        (o ? RIGHT : LEFT)[b * NN + c0 + pp] = sig;
    }
}

// ---------------- k_diagout: diag exp tile -> p -> psum atomics -> grid spin -> output -------
// grid 256 = 8 b x 32 i-tiles(64) (all co-resident on 256 CUs); block 256 = 4 waves.
// Wave wv handles dm1 = wv*16..wv*16+15; p values stay in registers across the spin.
__global__ __launch_bounds__(256) void k_diagout(const float* __restrict__ x,
                                                 const float* __restrict__ LEFT,
                                                 const float* __restrict__ RIGHT,
                                                 float* __restrict__ psum,
                                                 int* __restrict__ counter,
                                                 float* __restrict__ outp) {
    __shared__ float T[65][65];   // T[r][dm1] = exp(x[b, i0+r, i0+r+dm1+1]), +1 halo row
    __shared__ float psl[64];
    int b = blockIdx.x >> 5;
    int i0 = (blockIdx.x & 31) << 6;
    int tid = threadIdx.x;

    for (int idx = tid; idx < 65 * 64; idx += 256) {
        int r = idx >> 6, dm1 = idx & 63;
        int row = i0 + r;
        int col = row + dm1 + 1;
        float v = 0.f;
        if (row < NN && col < NN) v = __expf(x[((size_t)b * NN + row) * NN + col]);
        T[r][dm1] = v;
    }
    __syncthreads();

    int wv = tid >> 6, lane = tid & 63;
    int i = i0 + lane;
    const float* lf = LEFT + b * NN;
    const float* rt = RIGHT + b * NN;
    float pv[16];
#pragma unroll
    for (int s = 0; s < 16; s++) {
        int dm1 = wv * 16 + s;
        int d = dm1 + 1;
        int L = (NN - 1) - d;
        float p = 0.f;
        if (i < L) {
            float mi = T[lane + 1][dm1] * rt[i + 1] + T[lane][dm1] * lf[d + i];
            float mo = rt[i] + lf[d + 1 + i];
            p = __logf(mi / mo);
        }
        pv[s] = p;
        float s64 = p;
        for (int off = 32; off; off >>= 1) s64 += __shfl_down(s64, off);
        if (lane == 0) psl[dm1] = s64;
    }
    __syncthreads();
    if (tid < 64) atomicAdd(&psum[tid], psl[tid]);
    __syncthreads();
    if (tid == 0) {
        __threadfence();
        atomicAdd(counter, 1);
        while (__hip_atomic_load(counter, __ATOMIC_ACQUIRE, __HIP_MEMORY_SCOPE_AGENT) < 256) {}
    }
    __syncthreads();
    if (tid < 64)
        psl[tid] = __hip_atomic_load(&psum[tid], __ATOMIC_RELAXED, __HIP_MEMORY_SCOPE_AGENT);
    __syncthreads();

#pragma unroll
    for (int s = 0; s < 16; s++) {
        int dm1 = wv * 16 + s;
        int d = dm1 + 1;
        int L = (NN - 1) - d;
        if (i < L) {
            float mean = psl[dm1] / (float)(8 * L);
            size_t off0 = (size_t)dm1 * (NN - 1) - (size_t)dm1 * (dm1 + 1) / 2;
            outp[(size_t)b * TROW + off0 + i] = pv[s] - mean;
        }
    }
}

extern "C" void kernel_launch(void* const* d_in, const int* in_sizes, int n_in,
                              void* d_out, int out_size, void* d_ws, size_t ws_size,
                              hipStream_t stream) {
    const float* x = (const float*)d_in[0];
    const float* wl = (const float*)d_in[1];
    const float* bl = (const float*)d_in[2];
    const float* wr = (const float*)d_in[3];
    const float* br = (const float*)d_in[4];
    const float* wA = (const float*)d_in[5];
    const float* bA = (const float*)d_in[6];
    const float* wB = (const float*)d_in[7];
    const float* bB = (const float*)d_in[8];
    const float* wT = (const float*)d_in[9];
    const float* bT = (const float*)d_in[10];
    const float* wm = (const float*)d_in[11];
    const float* bm = (const float*)d_in[12];

    float* ws = (float*)d_ws;
    float* R    = ws;              // 8*2048*16        = 262144 f
    float* Rp   = ws + 262144;     // 4*8*2048*16      = 1048576 f
    float* CSp  = ws + 1310720;    // 16*8*16*2048     = 4194304 f
    float* CS   = ws + 5505024;    // 8*16*2048        = 262144 f
    float* LEFT = ws + 5767168;    // 8*2048           = 16384 f
    float* RIGHT= ws + 5783552;    // 8*2048           = 16384 f
    float* psum = ws + 5799936;    // 64 f
    int*   counter = (int*)(ws + 5800000);

    k_stage1<<<1280, 256, 0, stream>>>(x, wl, wr, Rp, CSp, psum, counter);
    k_csum<<<512, 256, 0, stream>>>(CSp, CS, Rp, R);
    k_chainC<<<128, 256, 0, stream>>>(R, CS, bl, br, wA, bA, wB, bB, wT, bT, wm, bm, LEFT, RIGHT);
    k_diagout<<<256, 256, 0, stream>>>(x, LEFT, RIGHT, psum, counter, (float*)d_out);
}